// Round 16
// baseline (127.698 us; speedup 1.0000x reference)
//
#include <hip/hip_runtime.h>
#include <math.h>

#define NOSC 2048
#define NB 16
#define DT 0.1f
#define M_TOT (NB * NOSC)    // 32768
#define KTP 2056             // padded LDS K row
#define NBLK_P 256           // persistent blocks: 128 i-tiles x 2 batch-halves

typedef __attribute__((ext_vector_type(8))) short bf16x8;
typedef __attribute__((ext_vector_type(4))) float f32x4;

__device__ __forceinline__ unsigned short f2bf(float x) {
    unsigned int u = __float_as_uint(x);
    u += 0x7FFFu + ((u >> 16) & 1u);          // round-to-nearest-even
    return (unsigned short)(u >> 16);
}
__device__ __forceinline__ float bf2f(unsigned short u) {
    return __uint_as_float(((unsigned int)u) << 16);
}

// Per-half fragment-tiled R layout. Half h (batches h*8..h*8+7) owns a
// 16x2048 table at R + h*M_TOT: row c16 = (b&7) for sin, 8+(b&7) for cos.
// idx(c16, j) = (j>>3)*128 + c16*8 + (j&7). Wave w's MFMA A-fragment k is
// contiguous at [w*2048 + k*512 + lane*8 .. +8).
__device__ __forceinline__ int ridx(int c16, int j) {
    return ((j >> 3) << 7) + (c16 << 3) + (j & 7);
}

// ---- agent-scope RELAXED helpers (sc1: bypass L2, coherent at L3) ----
__device__ __forceinline__ bf16x8 loadR16(const unsigned short* p) {
    union { unsigned long long u[2]; bf16x8 v; } x;
    x.u[0] = __hip_atomic_load((const unsigned long long*)p,
                               __ATOMIC_RELAXED, __HIP_MEMORY_SCOPE_AGENT);
    x.u[1] = __hip_atomic_load((const unsigned long long*)p + 1,
                               __ATOMIC_RELAXED, __HIP_MEMORY_SCOPE_AGENT);
    return x.v;
}
__device__ __forceinline__ void storeU32(unsigned short* p, unsigned int v) {
    __hip_atomic_store((unsigned int*)p, v,
                       __ATOMIC_RELAXED, __HIP_MEMORY_SCOPE_AGENT);
}

// Two-level fence-free grid barrier (per-step counter block: [root][8 groups]).
// Release = vmcnt(0) drain (sc1 stores visible at L3); arrivals/polls RELAXED.
__device__ __forceinline__ void gbar(unsigned int* base, int t, int bx) {
    asm volatile("s_waitcnt vmcnt(0)" ::: "memory");
    __syncthreads();
    if (t == 0) {
        const int g = bx >> 5;               // 8 groups of 32 blocks
        unsigned int tk = __hip_atomic_fetch_add(base + 1 + g, 1u,
                              __ATOMIC_RELAXED, __HIP_MEMORY_SCOPE_AGENT);
        if (tk == 31u)                       // last of group promotes to root
            __hip_atomic_fetch_add(base, 1u,
                              __ATOMIC_RELAXED, __HIP_MEMORY_SCOPE_AGENT);
        while (__hip_atomic_load(base, __ATOMIC_RELAXED,
                                 __HIP_MEMORY_SCOPE_AGENT) < 8u)
            __builtin_amdgcn_s_sleep(1);
    }
    __syncthreads();
}

// ws layout:
//   persistent path: [cnt 11*16 u32][accum 32 f32] at base
//   fallback path:   Kb[2048][2048] bf16 at base (8 MB) — paths never coexist
//   both: RA / RB bf16 R-buffers at base + 8 MB (128 KB each)

__global__ void zero_kernel(unsigned int* cnt, float* accum) {
    const int t = threadIdx.x;
    if (t < 11 * 16) cnt[t] = 0u;
    if (t < 32) accum[t] = 0.0f;
}

// ---------------- persistent cooperative kernel ----------------
// 256 blocks x 1024 thr (1 block/CU). Block bx: itile = bx>>1, h = bx&1.
// Owns i in [itile*16, +16) x batches [h*8, h*8+8) (both sin & cos rows).
// K tile in LDS for ALL steps; theta/sin/cos in registers; R via L3 atomics.
// Wave w = k-sixteenth: ONE A fragment set (16 rows = 8 sin + 8 cos), 4 MFMAs.
__global__ __launch_bounds__(1024, 4) void mega_kernel(
    const float* __restrict__ theta_in,
    const float* __restrict__ Kmat,
    const float* __restrict__ omega,
    const float* __restrict__ kg,
    const float* __restrict__ mod,
    float* __restrict__ th,
    float* __restrict__ coh,
    unsigned short* __restrict__ RA,
    unsigned short* __restrict__ RB,
    unsigned int* __restrict__ cnt,
    float* __restrict__ accum)
{
    __shared__ unsigned short Kt[16][KTP];          // 64.25 KB, persistent
    __shared__ float part[16][64][4];               // 16 KB
    __shared__ float coup[16][16];                  // 1 KB

    const int t = threadIdx.x;
    const int lane = t & 63;
    const int w = t >> 6;                            // wave = k-sixteenth
    const int bx = blockIdx.x;
    const int itile = bx >> 1;                       // adjacent blocks share K tile
    const int h = bx & 1;                            // batch-half
    const int i0 = itile * 16;
    const int rl = lane & 15;
    const int kbase = w * 128 + ((lane >> 4) << 3);

    // ---- one-time: convert own K tile (16 rows, 128 KB fp32) to LDS
    {
        const float4* __restrict__ src =
            reinterpret_cast<const float4*>(Kmat + (size_t)i0 * NOSC);
#pragma unroll
        for (int p = 0; p < 8; ++p) {
            const int q = t + p * 1024;              // float4 index 0..8191
            float4 v = src[q];
            ushort4 u = {f2bf(v.x), f2bf(v.y), f2bf(v.z), f2bf(v.w)};
            *reinterpret_cast<ushort4*>(&Kt[q >> 9][(q & 511) * 4]) = u;
        }
    }

    // ---- one-time: own theta state into registers, publish R0 (tiled layout)
    float th_o = 0.0f, sin_i = 0.0f, cos_i = 0.0f, om_i = 0.0f;
    float ws = 0.0f, wc = 0.0f;
    size_t o_upd = 0; int bs = 0, il = 0, Ls = 0, Lc = 0;
    if (t < 128) {
        bs = t >> 4; il = t & 15;                    // bs 0..7, il 0..15
        const int b2 = h * 8 + bs;
        o_upd = (size_t)b2 * NOSC + i0 + il;
        Ls = h * M_TOT + ridx(bs, i0 + il);          // sin slot
        Lc = h * M_TOT + ridx(8 + bs, i0 + il);      // cos slot
        om_i = omega[i0 + il];
        th_o = theta_in[o_upd];
        sincosf(th_o, &sin_i, &cos_i);
        float sn = __shfl_down(sin_i, 1), cn = __shfl_down(cos_i, 1);
        if ((il & 1) == 0) {
            storeU32(RA + Ls, (unsigned)f2bf(sin_i) | ((unsigned)f2bf(sn) << 16));
            storeU32(RA + Lc, (unsigned)f2bf(cos_i) | ((unsigned)f2bf(cn) << 16));
        }
    }
    const float scale = kg[0] * (1.0f + mod[0]) * (1.0f / (float)NOSC);

    gbar(&cnt[0], t, bx);       // R0 complete everywhere

    const unsigned short* Rcur = RA;
    unsigned short* Rnxt = RB;

    for (int s = 0; s < 10; ++s) {
        // ONE A fragment set (16 rows: 8 sin + 8 cos of this half), B from LDS
        bf16x8 afr[4], bfr[4];
        const unsigned short* pa = Rcur + h * M_TOT + (w << 11) + (lane << 3);
#pragma unroll
        for (int k = 0; k < 4; ++k) {
            afr[k] = loadR16(pa + (k << 9));
            bfr[k] = *reinterpret_cast<const bf16x8*>(&Kt[rl][kbase + k * 32]);
        }
        f32x4 acc = {0.0f, 0.0f, 0.0f, 0.0f};
#pragma unroll
        for (int k = 0; k < 4; ++k)
            acc = __builtin_amdgcn_mfma_f32_16x16x32_bf16(afr[k], bfr[k], acc, 0, 0, 0);

        *reinterpret_cast<f32x4*>(&part[w][lane][0]) = acc;
        __syncthreads();

        if (t < 256) {                               // reduce 16 k-partials
            const int c16 = t >> 4, ilr = t & 15;    // D row c16, col ilr
            const int ln = ((c16 >> 2) << 4) | ilr, rg = c16 & 3;
            float sum = 0.0f;
#pragma unroll
            for (int q = 0; q < 16; ++q) sum += part[q][ln][rg];
            coup[c16][ilr] = sum;
        }
        __syncthreads();

        if (t < 128) {                               // theta update (in-register)
            const float aS = coup[bs][il];           // sin-dot rows 0..7
            const float aC = coup[8 + bs][il];       // cos-dot rows 8..15
            float nt = th_o + DT * (om_i + scale * (cos_i * aS - sin_i * aC));
            sincosf(nt, &ws, &wc);
            if (s == 9) {
                th[o_upd] = atan2f(ws, wc);          // final wrap to (-pi, pi]
            } else {
                // wrap only shifts by 2*pi*k -> sin/cos unchanged; defer atan2
                th_o = nt; sin_i = ws; cos_i = wc;
                float sn = __shfl_down(ws, 1), cn = __shfl_down(wc, 1);
                if ((il & 1) == 0) {
                    storeU32(Rnxt + Ls, (unsigned)f2bf(ws) | ((unsigned)f2bf(sn) << 16));
                    storeU32(Rnxt + Lc, (unsigned)f2bf(wc) | ((unsigned)f2bf(cn) << 16));
                }
            }
        }
        if (s < 9) {
            gbar(&cnt[(s + 1) * 16], t, bx);
            const unsigned short* tmp = Rcur;
            Rcur = Rnxt; Rnxt = (unsigned short*)tmp;
        }
    }

    // ---- fused coherence: sum final ws/wc over this block's 16 i per batch
    if (t < 128) {
#pragma unroll
        for (int m = 1; m < 16; m <<= 1) {
            ws += __shfl_xor(ws, m);
            wc += __shfl_xor(wc, m);
        }
        if (il == 0) {
            const int b2 = h * 8 + bs;
            __hip_atomic_fetch_add(&accum[b2], ws, __ATOMIC_RELAXED, __HIP_MEMORY_SCOPE_AGENT);
            __hip_atomic_fetch_add(&accum[16 + b2], wc, __ATOMIC_RELAXED, __HIP_MEMORY_SCOPE_AGENT);
        }
    }
    gbar(&cnt[10 * 16], t, bx);
    if (bx == 0 && t < 16) {
        float ss = __hip_atomic_load(&accum[t], __ATOMIC_RELAXED, __HIP_MEMORY_SCOPE_AGENT)
                   * (1.0f / (float)NOSC);
        float cc = __hip_atomic_load(&accum[16 + t], __ATOMIC_RELAXED, __HIP_MEMORY_SCOPE_AGENT)
                   * (1.0f / (float)NOSC);
        coh[t] = sqrtf(ss * ss + cc * cc);
    }
}

// ---------------- fallback: multi-dispatch path (row-major R, self-consistent) ----------------
__global__ void init_kernel(const float* __restrict__ th_in,
                            float* __restrict__ th,
                            unsigned short* __restrict__ R0) {
    const int o4 = (blockIdx.x * 256 + threadIdx.x) * 4;
    if (o4 < M_TOT) {
        float4 v = *reinterpret_cast<const float4*>(th_in + o4);
        *reinterpret_cast<float4*>(th + o4) = v;
        float s0, c0, s1, c1, s2, c2, s3, c3;
        sincosf(v.x, &s0, &c0); sincosf(v.y, &s1, &c1);
        sincosf(v.z, &s2, &c2); sincosf(v.w, &s3, &c3);
        ushort4 us = {f2bf(s0), f2bf(s1), f2bf(s2), f2bf(s3)};
        ushort4 uc = {f2bf(c0), f2bf(c1), f2bf(c2), f2bf(c3)};
        *reinterpret_cast<ushort4*>(R0 + o4) = us;
        *reinterpret_cast<ushort4*>(R0 + M_TOT + o4) = uc;
    }
}

template <bool FIRST, bool FINAL>
__global__ __launch_bounds__(1024, 4) void step_kernel(
    const float* __restrict__ Kmat,
    unsigned short* __restrict__ Kb,
    const unsigned short* __restrict__ Rc,
    unsigned short* __restrict__ Rn,
    const float* __restrict__ omega,
    const float* __restrict__ kg,
    const float* __restrict__ mod,
    float* __restrict__ th)
{
    __shared__ float part[16][2][64][4];
    __shared__ float coup[32][16];

    const int t = threadIdx.x;
    const int lane = t & 63;
    const int w = t >> 6;
    const int i0 = blockIdx.x * 16;

    float th_o = 0.0f, sin_i = 0.0f, cos_i = 0.0f, om_i = 0.0f;
    size_t o_upd = 0;
    if (t < 256) {
        const int b2 = t >> 4;
        const int il = t & 15;
        o_upd = (size_t)b2 * NOSC + i0 + il;
        th_o = th[o_upd];
        sin_i = bf2f(Rc[o_upd]);
        cos_i = bf2f(Rc[M_TOT + o_upd]);
        om_i = omega[i0 + il];
    }
    const float scale = kg[0] * (1.0f + mod[0]) * (1.0f / (float)NOSC);

    const int rl = lane & 15;
    const int kbase = w * 128 + ((lane >> 4) << 3);
    const unsigned short* __restrict__ pas = Rc + (size_t)rl * NOSC + kbase;
    const unsigned short* __restrict__ pac = Rc + (size_t)(16 + rl) * NOSC + kbase;

    bf16x8 as[4], ac[4], bb[4];
    if constexpr (FIRST) {
        __shared__ unsigned short Kt[16][KTP];
        const float4* __restrict__ src =
            reinterpret_cast<const float4*>(Kmat + (size_t)i0 * NOSC);
#pragma unroll
        for (int p = 0; p < 8; ++p) {
            const int q = t + p * 1024;
            float4 v = src[q];
            ushort4 u = {f2bf(v.x), f2bf(v.y), f2bf(v.z), f2bf(v.w)};
            const int row = q >> 9;
            const int col = (q & 511) * 4;
            *reinterpret_cast<ushort4*>(&Kt[row][col]) = u;
            *reinterpret_cast<ushort4*>(Kb + (size_t)(i0 + row) * NOSC + col) = u;
        }
        __syncthreads();
#pragma unroll
        for (int k = 0; k < 4; ++k)
            bb[k] = *reinterpret_cast<const bf16x8*>(&Kt[rl][kbase + k * 32]);
    } else {
        const unsigned short* __restrict__ pbg = Kb + (size_t)(i0 + rl) * NOSC + kbase;
#pragma unroll
        for (int k = 0; k < 4; ++k)
            bb[k] = *reinterpret_cast<const bf16x8*>(pbg + k * 32);
    }
#pragma unroll
    for (int k = 0; k < 4; ++k) {
        as[k] = *reinterpret_cast<const bf16x8*>(pas + k * 32);
        ac[k] = *reinterpret_cast<const bf16x8*>(pac + k * 32);
    }

    f32x4 acc_s = {0.0f, 0.0f, 0.0f, 0.0f};
    f32x4 acc_c = {0.0f, 0.0f, 0.0f, 0.0f};
#pragma unroll
    for (int k = 0; k < 4; ++k) {
        acc_s = __builtin_amdgcn_mfma_f32_16x16x32_bf16(as[k], bb[k], acc_s, 0, 0, 0);
        acc_c = __builtin_amdgcn_mfma_f32_16x16x32_bf16(ac[k], bb[k], acc_c, 0, 0, 0);
    }
    *reinterpret_cast<f32x4*>(&part[w][0][lane][0]) = acc_s;
    *reinterpret_cast<f32x4*>(&part[w][1][lane][0]) = acc_c;
    __syncthreads();

    if (t < 512) {
        const int c = t >> 4, il = t & 15;
        const int half = c >> 4, cl = c & 15;
        const int ln = ((cl >> 2) << 4) | il, rg = cl & 3;
        float s = 0.0f;
#pragma unroll
        for (int q = 0; q < 16; ++q) s += part[q][half][ln][rg];
        coup[c][il] = s;
    }
    __syncthreads();

    if (t < 256) {
        const int b2 = t >> 4;
        const int il = t & 15;
        const float aS = coup[b2][il];
        const float aC = coup[16 + b2][il];
        float nt = th_o + DT * (om_i + scale * (cos_i * aS - sin_i * aC));
        float ws, wc;
        sincosf(nt, &ws, &wc);
        th[o_upd] = FINAL ? atan2f(ws, wc) : nt;
        Rn[o_upd] = f2bf(ws);
        Rn[M_TOT + o_upd] = f2bf(wc);
    }
}

__global__ void coherence_kernel(const unsigned short* __restrict__ R,
                                 float* __restrict__ coh) {
    const int b = blockIdx.x;
    const int t = threadIdx.x;
    float ss = 0.0f, sc = 0.0f;
    for (int j = t; j < NOSC; j += 256) {
        ss += bf2f(R[(size_t)b * NOSC + j]);
        sc += bf2f(R[M_TOT + (size_t)b * NOSC + j]);
    }
    for (int off = 32; off > 0; off >>= 1) {
        ss += __shfl_down(ss, off);
        sc += __shfl_down(sc, off);
    }
    __shared__ float red[8];
    const int w = t >> 6;
    if ((t & 63) == 0) { red[w * 2] = sc; red[w * 2 + 1] = ss; }
    __syncthreads();
    if (t == 0) {
        float tc = 0.0f, ts = 0.0f;
        for (int k = 0; k < 4; ++k) { tc += red[k * 2]; ts += red[k * 2 + 1]; }
        tc /= (float)NOSC;
        ts /= (float)NOSC;
        coh[b] = sqrtf(tc * tc + ts * ts);
    }
}

extern "C" void kernel_launch(void* const* d_in, const int* in_sizes, int n_in,
                              void* d_out, int out_size, void* d_ws, size_t ws_size,
                              hipStream_t stream) {
    const float* theta_in = (const float*)d_in[0];
    const float* Kmat     = (const float*)d_in[1];
    const float* omega    = (const float*)d_in[2];
    const float* kg       = (const float*)d_in[3];
    const float* mod      = (const float*)d_in[4];

    float* th  = (float*)d_out;               // [NB][NOSC] final theta
    float* coh = (float*)d_out + M_TOT;       // [NB]

    // persistent-path control block at ws base (overlaps fallback's Kb — exclusive)
    unsigned int* cnt = (unsigned int*)d_ws;              // 11*16 u32
    float* accum = (float*)d_ws + 192;                    // 32 f32
    unsigned short* Kb = (unsigned short*)d_ws;           // 8 MB (fallback only)
    unsigned short* RA = (unsigned short*)d_ws + (size_t)NOSC * NOSC; // 128 KB
    unsigned short* RB = RA + 2 * M_TOT;                              // 128 KB

    zero_kernel<<<1, 256, 0, stream>>>(cnt, accum);

    void* args[] = {(void*)&theta_in, (void*)&Kmat, (void*)&omega,
                    (void*)&kg, (void*)&mod, (void*)&th, (void*)&coh,
                    (void*)&RA, (void*)&RB, (void*)&cnt, (void*)&accum};
    hipError_t err = hipLaunchCooperativeKernel((const void*)mega_kernel,
                                                dim3(NBLK_P), dim3(1024),
                                                args, 0, stream);
    if (err != hipSuccess) {
        // fallback: proven multi-dispatch path (overwrites cnt region as Kb)
        init_kernel<<<32, 256, 0, stream>>>(theta_in, th, RA);
        for (int s = 0; s < 10; ++s) {
            const unsigned short* rc = (s & 1) ? RB : RA;
            unsigned short* rn = (s & 1) ? RA : RB;
            if (s == 0)
                step_kernel<true, false><<<NOSC / 16, 1024, 0, stream>>>(
                    Kmat, Kb, rc, rn, omega, kg, mod, th);
            else if (s < 9)
                step_kernel<false, false><<<NOSC / 16, 1024, 0, stream>>>(
                    Kmat, Kb, rc, rn, omega, kg, mod, th);
            else
                step_kernel<false, true><<<NOSC / 16, 1024, 0, stream>>>(
                    Kmat, Kb, rc, rn, omega, kg, mod, th);
        }
        coherence_kernel<<<NB, 256, 0, stream>>>(RA, coh);
    }
}

// Round 17
// 106.121 us; speedup vs baseline: 1.2033x; 1.2033x over previous
//
#include <hip/hip_runtime.h>
#include <math.h>

#define NOSC 2048
#define NB 16
#define DT 0.1f
#define M_TOT (NB * NOSC)    // 32768
#define KTP 2056             // padded LDS K row
#define NBLK_P 128           // persistent blocks (1 per CU, half the GPU)
#define NSTEP 10

typedef __attribute__((ext_vector_type(8))) short bf16x8;
typedef __attribute__((ext_vector_type(4))) float f32x4;

__device__ __forceinline__ unsigned short f2bf(float x) {
    unsigned int u = __float_as_uint(x);
    u += 0x7FFFu + ((u >> 16) & 1u);          // round-to-nearest-even
    return (unsigned short)(u >> 16);
}
__device__ __forceinline__ float bf2f(unsigned short u) {
    return __uint_as_float(((unsigned int)u) << 16);
}

// fragment-tiled R layout: sin idx(c,j) = (j>>3)*128 + c*8 + (j&7); cos +M_TOT.
// Wave w's MFMA A-fragment k = contiguous [w*2048 + k*512 + lane*8 .. +8) shorts.
__device__ __forceinline__ int ridx(int c, int j) {
    return ((j >> 3) << 7) + (c << 3) + (j & 7);
}

// ---- agent-scope RELAXED helpers (sc1: bypass L2, coherent at L3) ----
__device__ __forceinline__ bf16x8 loadR16(const unsigned short* p) {
    union { unsigned long long u[2]; bf16x8 v; } x;
    x.u[0] = __hip_atomic_load((const unsigned long long*)p,
                               __ATOMIC_RELAXED, __HIP_MEMORY_SCOPE_AGENT);
    x.u[1] = __hip_atomic_load((const unsigned long long*)p + 1,
                               __ATOMIC_RELAXED, __HIP_MEMORY_SCOPE_AGENT);
    return x.v;
}
__device__ __forceinline__ void storeU32(unsigned short* p, unsigned int v) {
    __hip_atomic_store((unsigned int*)p, v,
                       __ATOMIC_RELAXED, __HIP_MEMORY_SCOPE_AGENT);
}

// ws layout (persistent path):
//   F[NSTEP*128] u32 flags | ticket u32 | accum[32] f32       (control, ~5.3 KB)
//   at byte offset 8192: R slabs, NSTEP x (2*M_TOT shorts = 128 KB) = 1.25 MB
// fallback path overlays Kb[8 MB] at base + RA/RB after — paths never coexist.

__global__ void zero_kernel(unsigned int* F, unsigned int* ticket, float* accum) {
    const int t = threadIdx.x;
    for (int i = t; i < NSTEP * 128; i += 1024) F[i] = 0u;
    if (t == 0) *ticket = 0u;
    if (t < 32) accum[t] = 0.0f;
}

// ---------------- persistent dataflow kernel ----------------
// 128 blocks x 1024 thr. Block owns i in [bx*16, bx*16+16) (all 16 batches).
// K tile in LDS for ALL steps; theta/sin/cos in registers; R via L3 atomics.
// NO global barrier: per-step flags F[s][bx]; wave w waits only on its 8
// producers (blocks 8w..8w+7) — blocks pipeline instead of convoying.
__global__ __launch_bounds__(1024, 4) void mega_kernel(
    const float* __restrict__ theta_in,
    const float* __restrict__ Kmat,
    const float* __restrict__ omega,
    const float* __restrict__ kg,
    const float* __restrict__ mod,
    float* __restrict__ th,
    float* __restrict__ coh,
    unsigned short* __restrict__ Rb,     // NSTEP slabs of 2*M_TOT shorts
    unsigned int* __restrict__ F,
    unsigned int* __restrict__ ticket,
    float* __restrict__ accum)
{
    __shared__ unsigned short Kt[16][KTP];          // 64.25 KB, persistent
    __shared__ float part[16][2][64][4];            // 32 KB
    __shared__ float coup[32][16];                  // 2 KB

    const int t = threadIdx.x;
    const int lane = t & 63;
    const int w = t >> 6;                            // wave = k-sixteenth
    const int bx = blockIdx.x;
    const int i0 = bx * 16;
    const int rl = lane & 15;
    const int kbase = w * 128 + ((lane >> 4) << 3);

    // ---- one-time: convert own K tile (16 rows, 128 KB fp32 contiguous) to LDS
    {
        const float4* __restrict__ src =
            reinterpret_cast<const float4*>(Kmat + (size_t)i0 * NOSC);
#pragma unroll
        for (int p = 0; p < 8; ++p) {
            const int q = t + p * 1024;              // float4 index 0..8191
            float4 v = src[q];
            ushort4 u = {f2bf(v.x), f2bf(v.y), f2bf(v.z), f2bf(v.w)};
            *reinterpret_cast<ushort4*>(&Kt[q >> 9][(q & 511) * 4]) = u;
        }
    }

    // ---- one-time: own theta state into registers, publish R slab 0
    float th_o = 0.0f, sin_i = 0.0f, cos_i = 0.0f, om_i = 0.0f;
    float ws = 0.0f, wc = 0.0f;
    size_t o_upd = 0; int b2 = 0, il = 0, Lr = 0;
    if (t < 256) {
        b2 = t >> 4; il = t & 15;
        o_upd = (size_t)b2 * NOSC + i0 + il;
        Lr = ridx(b2, i0 + il);
        om_i = omega[i0 + il];
        th_o = theta_in[o_upd];
        sincosf(th_o, &sin_i, &cos_i);
        float sn = __shfl_down(sin_i, 1), cn = __shfl_down(cos_i, 1);
        if ((il & 1) == 0) {
            storeU32(Rb + Lr, (unsigned)f2bf(sin_i) | ((unsigned)f2bf(sn) << 16));
            storeU32(Rb + M_TOT + Lr, (unsigned)f2bf(cos_i) | ((unsigned)f2bf(cn) << 16));
        }
    }
    const float scale = kg[0] * (1.0f + mod[0]) * (1.0f / (float)NOSC);

    // publish flag for step-0 input (also orders Kt via the syncthreads)
    asm volatile("s_waitcnt vmcnt(0)" ::: "memory");
    __syncthreads();
    if (t == 0)
        __hip_atomic_store(&F[bx], 1u, __ATOMIC_RELAXED, __HIP_MEMORY_SCOPE_AGENT);

    for (int s = 0; s < NSTEP; ++s) {
        // ---- wave-level producer wait: blocks 8w..8w+7 must have published R[s]
        {
            const unsigned int* fp = F + s * 128 + w * 8;
            int ok = 0;
            do {
                unsigned int v = 1u;
                if (lane < 8 && (w * 8 + lane) != bx)   // own flag implied
                    v = __hip_atomic_load(fp + lane, __ATOMIC_RELAXED,
                                          __HIP_MEMORY_SCOPE_AGENT);
                ok = __all(v != 0u);
                if (!ok) __builtin_amdgcn_s_sleep(2);
            } while (!ok);
        }

        const unsigned short* Rcur = Rb + (size_t)s * 2 * M_TOT;
        bf16x8 as[4], ac[4], bb[4];
        const unsigned short* pa = Rcur + (w << 11) + (lane << 3);
#pragma unroll
        for (int k = 0; k < 4; ++k) {
            as[k] = loadR16(pa + (k << 9));
            ac[k] = loadR16(pa + M_TOT + (k << 9));
            bb[k] = *reinterpret_cast<const bf16x8*>(&Kt[rl][kbase + k * 32]);
        }
        f32x4 acc_s = {0.0f, 0.0f, 0.0f, 0.0f};
        f32x4 acc_c = {0.0f, 0.0f, 0.0f, 0.0f};
#pragma unroll
        for (int k = 0; k < 4; ++k) {
            acc_s = __builtin_amdgcn_mfma_f32_16x16x32_bf16(as[k], bb[k], acc_s, 0, 0, 0);
            acc_c = __builtin_amdgcn_mfma_f32_16x16x32_bf16(ac[k], bb[k], acc_c, 0, 0, 0);
        }
        *reinterpret_cast<f32x4*>(&part[w][0][lane][0]) = acc_s;
        *reinterpret_cast<f32x4*>(&part[w][1][lane][0]) = acc_c;
        __syncthreads();

        if (t < 512) {                               // reduce 16 k-partials
            const int c = t >> 4, ilr = t & 15;
            const int half = c >> 4, cl = c & 15;
            const int ln = ((cl >> 2) << 4) | ilr, rg = cl & 3;
            float sum = 0.0f;
#pragma unroll
            for (int q = 0; q < 16; ++q) sum += part[q][half][ln][rg];
            coup[c][ilr] = sum;
        }
        __syncthreads();

        if (t < 256) {                               // theta update (in-register)
            const float aS = coup[b2][il];
            const float aC = coup[16 + b2][il];
            float nt = th_o + DT * (om_i + scale * (cos_i * aS - sin_i * aC));
            sincosf(nt, &ws, &wc);
            if (s == NSTEP - 1) {
                th[o_upd] = atan2f(ws, wc);          // final wrap to (-pi, pi]
            } else {
                // wrap only shifts by 2*pi*k -> sin/cos unchanged; defer atan2
                th_o = nt; sin_i = ws; cos_i = wc;
                unsigned short* Rn = Rb + (size_t)(s + 1) * 2 * M_TOT;
                float sn = __shfl_down(ws, 1), cn = __shfl_down(wc, 1);
                if ((il & 1) == 0) {
                    storeU32(Rn + Lr, (unsigned)f2bf(ws) | ((unsigned)f2bf(sn) << 16));
                    storeU32(Rn + M_TOT + Lr, (unsigned)f2bf(wc) | ((unsigned)f2bf(cn) << 16));
                }
            }
        }
        if (s < NSTEP - 1) {
            asm volatile("s_waitcnt vmcnt(0)" ::: "memory");   // slice at L3
            __syncthreads();
            if (t == 0)
                __hip_atomic_store(&F[(s + 1) * 128 + bx], 1u,
                                   __ATOMIC_RELAXED, __HIP_MEMORY_SCOPE_AGENT);
        }
    }

    // ---- fused coherence: sum final ws/wc over this block's 16 i per batch
    if (t < 256) {
#pragma unroll
        for (int m = 1; m < 16; m <<= 1) {
            ws += __shfl_xor(ws, m);
            wc += __shfl_xor(wc, m);
        }
        if (il == 0) {
            __hip_atomic_fetch_add(&accum[b2], ws, __ATOMIC_RELAXED, __HIP_MEMORY_SCOPE_AGENT);
            __hip_atomic_fetch_add(&accum[16 + b2], wc, __ATOMIC_RELAXED, __HIP_MEMORY_SCOPE_AGENT);
        }
    }
    // last block to arrive finalizes (accum RMWs drained before ticket RMW)
    asm volatile("s_waitcnt vmcnt(0)" ::: "memory");
    __syncthreads();
    if (t == 0) {
        unsigned int tk = __hip_atomic_fetch_add(ticket, 1u,
                              __ATOMIC_RELAXED, __HIP_MEMORY_SCOPE_AGENT);
        if (tk == NBLK_P - 1) {
            for (int b = 0; b < NB; ++b) {
                float ss = __hip_atomic_load(&accum[b], __ATOMIC_RELAXED,
                               __HIP_MEMORY_SCOPE_AGENT) * (1.0f / (float)NOSC);
                float cc = __hip_atomic_load(&accum[16 + b], __ATOMIC_RELAXED,
                               __HIP_MEMORY_SCOPE_AGENT) * (1.0f / (float)NOSC);
                coh[b] = sqrtf(ss * ss + cc * cc);
            }
        }
    }
}

// ---------------- fallback: proven multi-dispatch path (round 11) ----------------
__global__ void init_kernel(const float* __restrict__ th_in,
                            float* __restrict__ th,
                            unsigned short* __restrict__ R0) {
    const int o4 = (blockIdx.x * 256 + threadIdx.x) * 4;
    if (o4 < M_TOT) {
        float4 v = *reinterpret_cast<const float4*>(th_in + o4);
        *reinterpret_cast<float4*>(th + o4) = v;
        float s0, c0, s1, c1, s2, c2, s3, c3;
        sincosf(v.x, &s0, &c0); sincosf(v.y, &s1, &c1);
        sincosf(v.z, &s2, &c2); sincosf(v.w, &s3, &c3);
        ushort4 us = {f2bf(s0), f2bf(s1), f2bf(s2), f2bf(s3)};
        ushort4 uc = {f2bf(c0), f2bf(c1), f2bf(c2), f2bf(c3)};
        *reinterpret_cast<ushort4*>(R0 + o4) = us;
        *reinterpret_cast<ushort4*>(R0 + M_TOT + o4) = uc;
    }
}

template <bool FIRST, bool FINAL>
__global__ __launch_bounds__(1024, 4) void step_kernel(
    const float* __restrict__ Kmat,
    unsigned short* __restrict__ Kb,
    const unsigned short* __restrict__ Rc,
    unsigned short* __restrict__ Rn,
    const float* __restrict__ omega,
    const float* __restrict__ kg,
    const float* __restrict__ mod,
    float* __restrict__ th)
{
    __shared__ float part[16][2][64][4];
    __shared__ float coup[32][16];

    const int t = threadIdx.x;
    const int lane = t & 63;
    const int w = t >> 6;
    const int i0 = blockIdx.x * 16;

    float th_o = 0.0f, sin_i = 0.0f, cos_i = 0.0f, om_i = 0.0f;
    size_t o_upd = 0;
    if (t < 256) {
        const int b2 = t >> 4;
        const int il = t & 15;
        o_upd = (size_t)b2 * NOSC + i0 + il;
        th_o = th[o_upd];
        sin_i = bf2f(Rc[o_upd]);
        cos_i = bf2f(Rc[M_TOT + o_upd]);
        om_i = omega[i0 + il];
    }
    const float scale = kg[0] * (1.0f + mod[0]) * (1.0f / (float)NOSC);

    const int rl = lane & 15;
    const int kbase = w * 128 + ((lane >> 4) << 3);
    const unsigned short* __restrict__ pas = Rc + (size_t)rl * NOSC + kbase;
    const unsigned short* __restrict__ pac = Rc + (size_t)(16 + rl) * NOSC + kbase;

    bf16x8 as[4], ac[4], bb[4];
    if constexpr (FIRST) {
        __shared__ unsigned short Kt[16][KTP];
        const float4* __restrict__ src =
            reinterpret_cast<const float4*>(Kmat + (size_t)i0 * NOSC);
#pragma unroll
        for (int p = 0; p < 8; ++p) {
            const int q = t + p * 1024;
            float4 v = src[q];
            ushort4 u = {f2bf(v.x), f2bf(v.y), f2bf(v.z), f2bf(v.w)};
            const int row = q >> 9;
            const int col = (q & 511) * 4;
            *reinterpret_cast<ushort4*>(&Kt[row][col]) = u;
            *reinterpret_cast<ushort4*>(Kb + (size_t)(i0 + row) * NOSC + col) = u;
        }
        __syncthreads();
#pragma unroll
        for (int k = 0; k < 4; ++k)
            bb[k] = *reinterpret_cast<const bf16x8*>(&Kt[rl][kbase + k * 32]);
    } else {
        const unsigned short* __restrict__ pbg = Kb + (size_t)(i0 + rl) * NOSC + kbase;
#pragma unroll
        for (int k = 0; k < 4; ++k)
            bb[k] = *reinterpret_cast<const bf16x8*>(pbg + k * 32);
    }
#pragma unroll
    for (int k = 0; k < 4; ++k) {
        as[k] = *reinterpret_cast<const bf16x8*>(pas + k * 32);
        ac[k] = *reinterpret_cast<const bf16x8*>(pac + k * 32);
    }

    f32x4 acc_s = {0.0f, 0.0f, 0.0f, 0.0f};
    f32x4 acc_c = {0.0f, 0.0f, 0.0f, 0.0f};
#pragma unroll
    for (int k = 0; k < 4; ++k) {
        acc_s = __builtin_amdgcn_mfma_f32_16x16x32_bf16(as[k], bb[k], acc_s, 0, 0, 0);
        acc_c = __builtin_amdgcn_mfma_f32_16x16x32_bf16(ac[k], bb[k], acc_c, 0, 0, 0);
    }
    *reinterpret_cast<f32x4*>(&part[w][0][lane][0]) = acc_s;
    *reinterpret_cast<f32x4*>(&part[w][1][lane][0]) = acc_c;
    __syncthreads();

    if (t < 512) {
        const int c = t >> 4, il = t & 15;
        const int half = c >> 4, cl = c & 15;
        const int ln = ((cl >> 2) << 4) | il, rg = cl & 3;
        float s = 0.0f;
#pragma unroll
        for (int q = 0; q < 16; ++q) s += part[q][half][ln][rg];
        coup[c][il] = s;
    }
    __syncthreads();

    if (t < 256) {
        const int b2 = t >> 4;
        const int il = t & 15;
        const float aS = coup[b2][il];
        const float aC = coup[16 + b2][il];
        float nt = th_o + DT * (om_i + scale * (cos_i * aS - sin_i * aC));
        float ws, wc;
        sincosf(nt, &ws, &wc);
        th[o_upd] = FINAL ? atan2f(ws, wc) : nt;
        Rn[o_upd] = f2bf(ws);
        Rn[M_TOT + o_upd] = f2bf(wc);
    }
}

__global__ void coherence_kernel(const unsigned short* __restrict__ R,
                                 float* __restrict__ coh) {
    const int b = blockIdx.x;
    const int t = threadIdx.x;
    float ss = 0.0f, sc = 0.0f;
    for (int j = t; j < NOSC; j += 256) {
        ss += bf2f(R[(size_t)b * NOSC + j]);
        sc += bf2f(R[M_TOT + (size_t)b * NOSC + j]);
    }
    for (int off = 32; off > 0; off >>= 1) {
        ss += __shfl_down(ss, off);
        sc += __shfl_down(sc, off);
    }
    __shared__ float red[8];
    const int w = t >> 6;
    if ((t & 63) == 0) { red[w * 2] = sc; red[w * 2 + 1] = ss; }
    __syncthreads();
    if (t == 0) {
        float tc = 0.0f, ts = 0.0f;
        for (int k = 0; k < 4; ++k) { tc += red[k * 2]; ts += red[k * 2 + 1]; }
        tc /= (float)NOSC;
        ts /= (float)NOSC;
        coh[b] = sqrtf(tc * tc + ts * ts);
    }
}

extern "C" void kernel_launch(void* const* d_in, const int* in_sizes, int n_in,
                              void* d_out, int out_size, void* d_ws, size_t ws_size,
                              hipStream_t stream) {
    const float* theta_in = (const float*)d_in[0];
    const float* Kmat     = (const float*)d_in[1];
    const float* omega    = (const float*)d_in[2];
    const float* kg       = (const float*)d_in[3];
    const float* mod      = (const float*)d_in[4];

    float* th  = (float*)d_out;               // [NB][NOSC] final theta
    float* coh = (float*)d_out + M_TOT;       // [NB]

    // persistent-path control block (overlaps fallback's Kb — exclusive)
    unsigned int* F      = (unsigned int*)d_ws;                 // NSTEP*128 u32
    unsigned int* ticket = F + NSTEP * 128;                     // 1 u32
    float* accum         = (float*)(ticket + 1);                // 32 f32
    unsigned short* Rb   = (unsigned short*)((char*)d_ws + 8192);  // 10 x 128 KB

    unsigned short* Kb = (unsigned short*)d_ws;                       // fallback
    unsigned short* RA = (unsigned short*)d_ws + (size_t)NOSC * NOSC;
    unsigned short* RB = RA + 2 * M_TOT;

    zero_kernel<<<1, 1024, 0, stream>>>(F, ticket, accum);

    void* args[] = {(void*)&theta_in, (void*)&Kmat, (void*)&omega,
                    (void*)&kg, (void*)&mod, (void*)&th, (void*)&coh,
                    (void*)&Rb, (void*)&F, (void*)&ticket, (void*)&accum};
    hipError_t err = hipLaunchCooperativeKernel((const void*)mega_kernel,
                                                dim3(NBLK_P), dim3(1024),
                                                args, 0, stream);
    if (err != hipSuccess) {
        // fallback: proven multi-dispatch path (overwrites control region as Kb)
        init_kernel<<<32, 256, 0, stream>>>(theta_in, th, RA);
        for (int s = 0; s < 10; ++s) {
            const unsigned short* rc = (s & 1) ? RB : RA;
            unsigned short* rn = (s & 1) ? RA : RB;
            if (s == 0)
                step_kernel<true, false><<<NOSC / 16, 1024, 0, stream>>>(
                    Kmat, Kb, rc, rn, omega, kg, mod, th);
            else if (s < 9)
                step_kernel<false, false><<<NOSC / 16, 1024, 0, stream>>>(
                    Kmat, Kb, rc, rn, omega, kg, mod, th);
            else
                step_kernel<false, true><<<NOSC / 16, 1024, 0, stream>>>(
                    Kmat, Kb, rc, rn, omega, kg, mod, th);
        }
        coherence_kernel<<<NB, 256, 0, stream>>>(RA, coh);
    }
}